// Round 3
// baseline (600.506 us; speedup 1.0000x reference)
//
#include <hip/hip_runtime.h>
#include <stdint.h>

// Instant-NGP HashGrid forward, MI355X. Gather-bound.
// R4: revert nontemporal (R3: nt bypassed L2 -> FETCH 440MB->2.5GB, 2.3x dur).
// R5: baseline 394us kernel; VGPR=28, VALUBusy 12.5%, HBM 18%, all pipes
//     <40% -> latency-bound, ILP-starved.
// R6 FAILED: full unroll -> VGPR 32 only, compiler refuses cross-level load
//     hoisting, dur 408us. Lesson: must force pipelining structurally.
// R7: explicit 3-deep software pipeline. Each hashed level = issue (8 hash
//     indices + 8 independent dwordx2 gathers into named regs) + consume
//     (trilinear). Partner (x+1) corners loaded unconditionally: same 64B
//     line when x even, so no extra line traffic; kills divergent branch
//     and hi/lo selects. Depth 3 -> ~24 gathers/lane in flight. Levels 3-5
//     issued BEFORE dense 0-2 compute (L2-hot) to cover first round trip.
//     __launch_bounds__(256,4): 128-VGPR budget, 4 blocks/CU, 32KB LDS
//     single tile, one sync, one 8-round store phase.

#define NLVL 16
#define TS 65536
#define P2 2654435761u
#define P3 805459861u

typedef float v4f __attribute__((ext_vector_type(4)));
typedef float v2f __attribute__((ext_vector_type(2)));
// 8-byte-aligned float4 view for dense-path table loads.
typedef float v4fa8 __attribute__((ext_vector_type(4), aligned(8)));

__constant__ float C_SCALES[NLVL] = {
    15.0f, 23.0f, 35.0f, 53.0f, 80.0f, 120.5f, 181.25f, 272.375f,
    409.0625f, 614.09375f, 921.640625f, 1382.9609375f,
    2074.94140625f, 3112.912109375f, 4669.8681640625f, 7005.30224609375f};

__device__ __forceinline__ v2f v4lo8(v4fa8 v) { v2f r; r.x = v.x; r.y = v.y; return r; }
__device__ __forceinline__ v2f v4hi8(v4fa8 v) { v2f r; r.x = v.z; r.y = v.w; return r; }

// LDS: two 16KB tiles, [256 pts][4 float4 slots] each; level l -> tile
// t=l>>3, group gl=(l>>1)&3, half h=l&1; slot(p,gl)=(gl+p)&3.
__device__ __forceinline__ void lds_put2(float* s, int p, int l,
                                         float a, float b) {
    const int t = l >> 3;
    const int gl = (l >> 1) & 3;
    const int slot = (gl + p) & 3;
    const int a32 = t * 4096 + p * 16 + slot * 4 + (l & 1) * 2;  // 8B-aligned
    s[a32] = a;
    s[a32 + 1] = b;
}

// Pipeline state for one hashed level: 8 corner features + fracs.
struct LvlS {
    v2f c0, c1, c2, c3, c4, c5, c6, c7;  // 16 VGPR
    float wx, wy, wz;                    // 3 VGPR
};

__device__ __forceinline__ void lvl_issue(LvlS& s, float px, float py,
                                          float pz, float scale,
                                          const v2f* __restrict__ tbl) {
    const float fx = px * scale + 0.5f;
    const float fy = py * scale + 0.5f;
    const float fz = pz * scale + 0.5f;
    const float gx = floorf(fx), gy = floorf(fy), gz = floorf(fz);
    s.wx = fx - gx;
    s.wy = fy - gy;
    s.wz = fz - gz;
    const uint32_t bx = (uint32_t)(int)gx, bx1 = bx + 1;
    const uint32_t hy0 = (uint32_t)(int)gy * P2, hy1 = hy0 + P2;
    const uint32_t hz0 = (uint32_t)(int)gz * P3, hz1 = hz0 + P3;
    const uint32_t b00 = hy0 ^ hz0, b01 = hy0 ^ hz1;
    const uint32_t b10 = hy1 ^ hz0, b11 = hy1 ^ hz1;
    s.c0 = tbl[(bx ^ b00) & (TS - 1)];
    s.c1 = tbl[(bx ^ b01) & (TS - 1)];
    s.c2 = tbl[(bx ^ b10) & (TS - 1)];
    s.c3 = tbl[(bx ^ b11) & (TS - 1)];
    s.c4 = tbl[(bx1 ^ b00) & (TS - 1)];
    s.c5 = tbl[(bx1 ^ b01) & (TS - 1)];
    s.c6 = tbl[(bx1 ^ b10) & (TS - 1)];
    s.c7 = tbl[(bx1 ^ b11) & (TS - 1)];
}

__device__ __forceinline__ v2f lvl_consume(const LvlS& s) {
    const float ux = 1.0f - s.wx, uy = 1.0f - s.wy, uz = 1.0f - s.wz;
    const float w0 = ux * uy * uz, w1 = ux * uy * s.wz;
    const float w2 = ux * s.wy * uz, w3 = ux * s.wy * s.wz;
    const float w4 = s.wx * uy * uz, w5 = s.wx * uy * s.wz;
    const float w6 = s.wx * s.wy * uz, w7 = s.wx * s.wy * s.wz;
    v2f o;
    o.x = w0 * s.c0.x + w1 * s.c1.x + w2 * s.c2.x + w3 * s.c3.x +
          w4 * s.c4.x + w5 * s.c5.x + w6 * s.c6.x + w7 * s.c7.x;
    o.y = w0 * s.c0.y + w1 * s.c1.y + w2 * s.c2.y + w3 * s.c3.y +
          w4 * s.c4.y + w5 * s.c5.y + w6 * s.c6.y + w7 * s.c7.y;
    return o;
}

__global__ __launch_bounds__(256, 4) void hashgrid_fwd(
    const float* __restrict__ x,
    const float* __restrict__ table,
    float* __restrict__ out,
    int n)
{
    __shared__ float s_out[256 * 32];  // 32 KiB, two 16KB tiles

    const int tid0 = blockIdx.x * 256 + threadIdx.x;
    const int tid = min(tid0, n - 1);
    const int p = threadIdx.x;

    const float px = x[3 * tid + 0];
    const float py = x[3 * tid + 1];
    const float pz = x[3 * tid + 2];

    v4f* outb4 = (v4f*)out + (size_t)blockIdx.x * (256 * 8);
    const long long lim4 = (long long)n * 8 - (long long)blockIdx.x * (256 * 8);

    const v2f* tblv = (const v2f*)table;

    // ---- fire the first 3 hashed levels before anything else ----
    LvlS s0, s1, s2;
    lvl_issue(s0, px, py, pz, C_SCALES[3], tblv + (size_t)3 * TS);
    lvl_issue(s1, px, py, pz, C_SCALES[4], tblv + (size_t)4 * TS);
    lvl_issue(s2, px, py, pz, C_SCALES[5], tblv + (size_t)5 * TS);

    // ---- dense levels 0..2 (small tables, L2-hot) cover the latency ----
    {
        const int RESO[3] = {16, 24, 36};
        const float DSC[3] = {15.0f, 23.0f, 35.0f};
#pragma unroll
        for (int l = 0; l < 3; ++l) {
            const float scale = DSC[l];
            const float fx = px * scale + 0.5f;
            const float fy = py * scale + 0.5f;
            const float fz = pz * scale + 0.5f;
            const float gx = floorf(fx), gy = floorf(fy), gz = floorf(fz);
            const float wx = fx - gx, wy = fy - gy, wz = fz - gz;
            const int ix = (int)gx, iy = (int)gy, iz = (int)gz;

            const v2f* tbl = tblv + (size_t)l * TS;
            const int R = RESO[l];
            const int x0 = min(ix, R - 1);
            const int y0 = min(iy, R - 1), y1 = min(iy + 1, R - 1);
            const int z0 = min(iz, R - 1), z1 = min(iz + 1, R - 1);
            const int xb = min(x0, R - 2);
            const bool hi0 = (x0 != xb);
            const int y0R = y0 * R, y1R = y1 * R;
            const int z0R = z0 * R * R, z1R = z1 * R * R;
            const v4fa8 f00 = *(const v4fa8*)(tbl + (xb + y0R + z0R));
            const v4fa8 f01 = *(const v4fa8*)(tbl + (xb + y0R + z1R));
            const v4fa8 f10 = *(const v4fa8*)(tbl + (xb + y1R + z0R));
            const v4fa8 f11 = *(const v4fa8*)(tbl + (xb + y1R + z1R));
            const v2f c0 = hi0 ? v4hi8(f00) : v4lo8(f00), c4 = v4hi8(f00);
            const v2f c1 = hi0 ? v4hi8(f01) : v4lo8(f01), c5 = v4hi8(f01);
            const v2f c2 = hi0 ? v4hi8(f10) : v4lo8(f10), c6 = v4hi8(f10);
            const v2f c3 = hi0 ? v4hi8(f11) : v4lo8(f11), c7 = v4hi8(f11);

            const float ux = 1.0f - wx, uy = 1.0f - wy, uz = 1.0f - wz;
            const float w0 = ux * uy * uz, w1 = ux * uy * wz;
            const float w2 = ux * wy * uz, w3 = ux * wy * wz;
            const float w4 = wx * uy * uz, w5 = wx * uy * wz;
            const float w6 = wx * wy * uz, w7 = wx * wy * wz;

            const float o0 = w0 * c0.x + w1 * c1.x + w2 * c2.x + w3 * c3.x +
                             w4 * c4.x + w5 * c5.x + w6 * c6.x + w7 * c7.x;
            const float o1 = w0 * c0.y + w1 * c1.y + w2 * c2.y + w3 * c3.y +
                             w4 * c4.y + w5 * c5.y + w6 * c6.y + w7 * c7.y;
            lds_put2(s_out, p, l, o0, o1);
        }
    }

    // ---- depth-3 rotation over hashed levels 3..15 (static indices) ----
#define STEP(S, LCUR) { const v2f o = lvl_consume(S); lds_put2(s_out, p, LCUR, o.x, o.y); }
#define REISSUE(S, LNXT) lvl_issue(S, px, py, pz, C_SCALES[LNXT], tblv + (size_t)(LNXT) * TS);

    STEP(s0, 3)  REISSUE(s0, 6)
    STEP(s1, 4)  REISSUE(s1, 7)
    STEP(s2, 5)  REISSUE(s2, 8)
    STEP(s0, 6)  REISSUE(s0, 9)
    STEP(s1, 7)  REISSUE(s1, 10)
    STEP(s2, 8)  REISSUE(s2, 11)
    STEP(s0, 9)  REISSUE(s0, 12)
    STEP(s1, 10) REISSUE(s1, 13)
    STEP(s2, 11) REISSUE(s2, 14)
    STEP(s0, 12) REISSUE(s0, 15)
    STEP(s1, 13)
    STEP(s2, 14)
    STEP(s0, 15)
#undef STEP
#undef REISSUE

    __syncthreads();

    // ---- store: 8 rounds, 128B contiguous per 8 lanes ----
#pragma unroll
    for (int r = 0; r < 8; ++r) {
        const int e = r * 256 + threadIdx.x;   // 0..2047
        const int pp = e >> 3, q = e & 7;      // point, float4-in-point
        const int t = q >> 2, g = q & 3;
        const int slot = (g + pp) & 3;
        const v4f v = *(const v4f*)&s_out[t * 4096 + pp * 16 + slot * 4];
        const int o4 = pp * 8 + q;
        if (o4 < lim4) outb4[o4] = v;
    }
}

extern "C" void kernel_launch(void* const* d_in, const int* in_sizes, int n_in,
                              void* d_out, int out_size, void* d_ws, size_t ws_size,
                              hipStream_t stream) {
    const float* x = (const float*)d_in[0];     // [N,3] f32
    const float* table = (const float*)d_in[1]; // [16,65536,2] f32
    float* out = (float*)d_out;                 // [N,32] f32
    const int n = in_sizes[0] / 3;
    const int block = 256;
    const int grid = (n + block - 1) / block;
    hashgrid_fwd<<<grid, block, 0, stream>>>(x, table, out, n);
}